// Round 6
// baseline (443.506 us; speedup 1.0000x reference)
//
#include <hip/hip_runtime.h>
#include <hip/hip_bf16.h>
#include <cstdint>
#include <cstddef>

// Problem dims
#define M_ROWS   4096     // B*T
#define N_VOCAB  32000    // V
#define K_DIM    512      // D
#define S_DIM    400
#define CV_DIM   600
#define OUT_PITCH 32600   // V + CV
#define PAD_IDX  1

typedef __attribute__((ext_vector_type(8))) short short8;
typedef __attribute__((ext_vector_type(8))) unsigned short ushort8;
typedef __attribute__((ext_vector_type(4))) float f32x4;

// ws layout
#define WB_OFF   0ull                       // W bf16: 32,768,000 B
#define HB_OFF   32768000ull                // hidden bf16: 4,194,304 B
#define COPYG_OFF 36962304ull
#define RSUM_OFF  36978688ull
#define SSCALE_OFF 36995072ull
#define SRCID_OFF 37011456ull               // 51,200 B
#define EB_OFF    37062656ull               // bf16 exp intermediate: 262,144,000 B
#define WS_NEED_BF16 (EB_OFF + 262144000ull)

__device__ inline void gload_lds16(const void* g, void* l) {
  __builtin_amdgcn_global_load_lds(
      (const __attribute__((address_space(1))) unsigned int*)g,
      (__attribute__((address_space(3))) unsigned int*)l, 16, 0, 0);
}

__device__ inline unsigned short f32_to_bf16_rn(float f) {
  unsigned u = __float_as_uint(f);
  u += 0x7FFFu + ((u >> 16) & 1u);
  return (unsigned short)(u >> 16);
}
__device__ inline float bf16_to_f32(unsigned short h) {
  return __uint_as_float((unsigned)h << 16);
}

// ---------- K1a: fp32 -> bf16 conversion (vectorized) ----------
__global__ void cvt_kernel(const float4* __restrict__ in, ushort4* __restrict__ out, unsigned n4) {
  unsigned stride = gridDim.x * blockDim.x;
  for (unsigned i = blockIdx.x * blockDim.x + threadIdx.x; i < n4; i += stride) {
    float4 v = in[i];
    ushort4 o;
    o.x = f32_to_bf16_rn(v.x);
    o.y = f32_to_bf16_rn(v.y);
    o.z = f32_to_bf16_rn(v.z);
    o.w = f32_to_bf16_rn(v.w);
    out[i] = o;
  }
}

// ---------- K1b: copy gate ----------
__global__ void copygate_kernel(const float* __restrict__ hidden, const float* __restrict__ w_copy,
                                const float* __restrict__ b_copy, float* __restrict__ copyg) {
  unsigned gw = (blockIdx.x * blockDim.x + threadIdx.x) >> 6;
  unsigned lane = threadIdx.x & 63u;
  if (gw >= M_ROWS) return;
  const float4* h4 = (const float4*)(hidden + (size_t)gw * K_DIM);
  const float4* w4 = (const float4*)w_copy;
  float dot = 0.f;
  #pragma unroll
  for (int i = 0; i < 2; ++i) {
    float4 a = h4[lane * 2 + i], w = w4[lane * 2 + i];
    dot += a.x * w.x + a.y * w.y + a.z * w.z + a.w * w.w;
  }
  #pragma unroll
  for (int mask = 1; mask < 64; mask <<= 1) dot += __shfl_xor(dot, mask);
  if (lane == 0) copyg[gw] = 1.f / (1.f + __expf(-(dot + b_copy[0])));
}

// ---------- K1c: recover src_ids from one-hot src_map ----------
__global__ void srcids_kernel(const float* __restrict__ src_map, int* __restrict__ src_ids) {
  unsigned pos = (blockIdx.x * blockDim.x + threadIdx.x) >> 6;
  unsigned lane = threadIdx.x & 63u;
  if (pos >= 32 * S_DIM) return;
  const float* row = src_map + (size_t)pos * CV_DIM;
  int found = 1 << 30;
  for (int v = lane; v < CV_DIM; v += 64)
    if (row[v] > 0.5f) found = v;
  #pragma unroll
  for (int mask = 1; mask < 64; mask <<= 1) {
    int o = __shfl_xor(found, mask);
    found = found < o ? found : o;
  }
  if (lane == 0) src_ids[pos] = found;
}

// ---------- K2: 128x128 bf16 MFMA GEMM, BK=32 double-buffered 2-phase ----------
// 4 waves (2x2), 2 x 16 KB LDS buffers (32 KB total -> 4 blocks/CU preserved).
// Counted vmcnt(4): next tile's loads stay in flight across the barrier; no
// full drain in the main loop. Swizzle: ch = lr ^ (lc&3) ^ ((lc>>2)&3),
// inverse applied on global source (both-sides rule).
template<int BF16OUT>
__global__ __launch_bounds__(256, 4)
void gemm_exp_kernel(const unsigned short* __restrict__ A,
                     const unsigned short* __restrict__ B,
                     const float* __restrict__ bias,
                     float* __restrict__ out,
                     unsigned short* __restrict__ Eb,
                     float* __restrict__ row_sum) {
  // [buf:2][op:2 As|Bs][row:128][chunk:4][8 ushort] = 32 KB; reused for pack.
  __shared__ unsigned short smem[16384];

  unsigned bid = blockIdx.x;
  // bijective XCD swizzle: 8000 blocks, 8000 % 8 == 0
  unsigned wg = (bid & 7u) * 1000u + (bid >> 3);
  unsigned mt = wg / 250u, nt = wg % 250u;
  unsigned m0 = mt * 128u, n0 = nt * 128u;
  unsigned tid = threadIdx.x;
  unsigned lane = tid & 63u;
  unsigned wid = tid >> 6;
  unsigned wm = wid >> 1, wn = wid & 1u;    // 2 x 2 wave grid, 64x64 per wave
  unsigned lr = lane >> 4, lc = lane & 15u;

  // reader swizzled chunk (0..3): 2-way worst case = free
  const unsigned ch = lr ^ (lc & 3u) ^ ((lc >> 2) & 3u);

  // staging: unit u = i*256+tid -> row r=u>>2, lds chunk c=u&3, src chunk c^f(r)
  const unsigned short* AsrcP[2];
  const unsigned short* BsrcP[2];
  unsigned dstB[2];
  #pragma unroll
  for (unsigned i = 0; i < 2; ++i) {
    unsigned u = i * 256u + tid;
    unsigned r = u >> 2, c = u & 3u;
    unsigned cs = c ^ (r & 3u) ^ ((r >> 2) & 3u);
    dstB[i] = u * 16u;                       // byte offset within As-region of a buf
    AsrcP[i] = A + (size_t)(m0 + r) * K_DIM + cs * 8u;
    BsrcP[i] = B + (size_t)(n0 + r) * K_DIM + cs * 8u;
  }
  // fragment read indices (ushort units within a buf region)
  unsigned aidx[4], bidx[4];
  #pragma unroll
  for (int m = 0; m < 4; ++m) aidx[m] = (wm * 64u + m * 16u + lc) * 32u + ch * 8u;
  #pragma unroll
  for (int n = 0; n < 4; ++n) bidx[n] = 4096u + (wn * 64u + n * 16u + lc) * 32u + ch * 8u;

  auto STAGE = [&](unsigned buf, unsigned kt) {
    unsigned k0 = kt * 32u;
    char* base = (char*)smem + buf * 16384u;
    #pragma unroll
    for (unsigned i = 0; i < 2; ++i) {
      gload_lds16(AsrcP[i] + k0, base + dstB[i]);
      gload_lds16(BsrcP[i] + k0, base + 8192u + dstB[i]);
    }
  };

  f32x4 acc[4][4] = {};

  STAGE(0, 0);                               // 4 loads in flight
  #pragma unroll 4
  for (int kt = 0; kt < 16; ++kt) {
    unsigned bufo = ((unsigned)kt & 1u) * 8192u;   // ushort units
    if (kt < 15) {
      STAGE((unsigned)(kt + 1) & 1u, (unsigned)kt + 1u);   // 8 in flight
      asm volatile("s_waitcnt vmcnt(4)" ::: "memory");      // tile kt landed
    } else {
      asm volatile("s_waitcnt vmcnt(0)" ::: "memory");
    }
    __builtin_amdgcn_s_barrier();            // all waves' tile-kt loads visible
    asm volatile("" ::: "memory");
    __builtin_amdgcn_sched_barrier(0);
    {
      short8 af[4], bf[4];
      #pragma unroll
      for (int m = 0; m < 4; ++m) af[m] = *(const short8*)&smem[bufo + aidx[m]];
      #pragma unroll
      for (int n = 0; n < 4; ++n) bf[n] = *(const short8*)&smem[bufo + bidx[n]];
      #pragma unroll
      for (int m = 0; m < 4; ++m)
        #pragma unroll
        for (int n = 0; n < 4; ++n)
          acc[m][n] = __builtin_amdgcn_mfma_f32_16x16x32_bf16(af[m], bf[n],
                                                              acc[m][n], 0, 0, 0);
    }
    __builtin_amdgcn_s_barrier();            // reads done before buf reuse
    asm volatile("" ::: "memory");
  }

  // epilogue: e = exp(logit + bias); |logit| <~ 4 so no max-subtraction.
  float bv[4];
  #pragma unroll
  for (int n = 0; n < 4; ++n) bv[n] = bias[n0 + wn * 64u + n * 16u + lc];

  if (BF16OUT) {
    // exp + pack 128x128 bf16 tile via LDS (swizzled), coalesced stores to Eb.
    #pragma unroll
    for (int m = 0; m < 4; ++m)
      #pragma unroll
      for (int j = 0; j < 4; ++j) {
        unsigned r = wm * 64u + m * 16u + lr * 4u + j;
        #pragma unroll
        for (int n = 0; n < 4; ++n) {
          unsigned c = wn * 64u + n * 16u + lc;
          unsigned gcol = n0 + c;
          float e = (gcol == PAD_IDX) ? 0.f : __expf(acc[m][n][j] + bv[n]);
          smem[r * 128u + (c ^ ((r & 7u) << 3))] = f32_to_bf16_rn(e);
        }
      }
    __syncthreads();
    {
      unsigned r = tid >> 1, c0 = (tid & 1u) * 64u;
      unsigned short* gdst = Eb + (size_t)(m0 + r) * N_VOCAB + n0 + c0;
      #pragma unroll
      for (unsigned q = 0; q < 8; ++q) {
        ushort8 v = *(const ushort8*)&smem[r * 128u + c0 + ((q ^ (r & 7u)) << 3)];
        *(ushort8*)(gdst + q * 8u) = v;
      }
    }
  } else {
    // fallback: fp32 stores + atomic row sums
    #pragma unroll
    for (int m = 0; m < 4; ++m) {
      #pragma unroll
      for (int j = 0; j < 4; ++j) {
        unsigned grow = m0 + wm * 64u + m * 16u + lr * 4u + j;
        float rs = 0.f;
        #pragma unroll
        for (int n = 0; n < 4; ++n) {
          unsigned gcol = n0 + wn * 64u + n * 16u + lc;
          float e = (gcol == PAD_IDX) ? 0.f : __expf(acc[m][n][j] + bv[n]);
          out[(size_t)grow * OUT_PITCH + gcol] = e;
          rs += e;
        }
        #pragma unroll
        for (int mask = 1; mask < 16; mask <<= 1) rs += __shfl_xor(rs, mask);
        if (lc == 0) atomicAdd(&row_sum[grow], rs);
      }
    }
  }
}

// ---------- K3: per-row sum + scale: out = Eb * (1-gate)/sum ----------
__global__ __launch_bounds__(256)
void norm_scale_kernel(const unsigned short* __restrict__ Eb,
                       const float* __restrict__ copyg,
                       float* __restrict__ out) {
  unsigned r = blockIdx.x;
  unsigned tid = threadIdx.x;
  const ushort8* src = (const ushort8*)(Eb + (size_t)r * N_VOCAB);   // 4000 chunks
  ushort8 v[16];
  float lsum = 0.f;
  #pragma unroll
  for (int i = 0; i < 16; ++i) {
    unsigned c = (unsigned)i * 256u + tid;
    if (c < 4000u) {
      v[i] = src[c];
      #pragma unroll
      for (int k = 0; k < 8; ++k) lsum += bf16_to_f32(v[i][k]);
    }
  }
  #pragma unroll
  for (int mask = 1; mask < 64; mask <<= 1) lsum += __shfl_xor(lsum, mask);
  __shared__ float wsum[4];
  if ((tid & 63u) == 0) wsum[tid >> 6] = lsum;
  __syncthreads();
  float s = (1.f - copyg[r]) / (wsum[0] + wsum[1] + wsum[2] + wsum[3]);
  float* dst = out + (size_t)r * OUT_PITCH;
  #pragma unroll
  for (int i = 0; i < 16; ++i) {
    unsigned c = (unsigned)i * 256u + tid;
    if (c < 4000u) {
      float4 lo, hi;
      lo.x = bf16_to_f32(v[i][0]) * s; lo.y = bf16_to_f32(v[i][1]) * s;
      lo.z = bf16_to_f32(v[i][2]) * s; lo.w = bf16_to_f32(v[i][3]) * s;
      hi.x = bf16_to_f32(v[i][4]) * s; hi.y = bf16_to_f32(v[i][5]) * s;
      hi.z = bf16_to_f32(v[i][6]) * s; hi.w = bf16_to_f32(v[i][7]) * s;
      float4* o = (float4*)(dst + c * 8u);
      o[0] = lo; o[1] = hi;
    }
  }
}

// ---------- fallback-path kernels ----------
__global__ void finalize_kernel(const float* __restrict__ row_sum, const float* __restrict__ copyg,
                                float* __restrict__ sscale) {
  unsigned r = blockIdx.x * blockDim.x + threadIdx.x;
  if (r < M_ROWS) sscale[r] = (1.f - copyg[r]) / row_sum[r];
}

__global__ void scale_kernel(float4* __restrict__ out, const float* __restrict__ sscale) {
  const unsigned total = M_ROWS * (N_VOCAB / 4);
  unsigned stride = gridDim.x * blockDim.x;
  for (unsigned i = blockIdx.x * blockDim.x + threadIdx.x; i < total; i += stride) {
    unsigned r = i / (N_VOCAB / 4);
    unsigned c = i % (N_VOCAB / 4);
    float s = sscale[r];
    float4 v = out[(size_t)r * (OUT_PITCH / 4) + c];
    v.x *= s; v.y *= s; v.z *= s; v.w *= s;
    out[(size_t)r * (OUT_PITCH / 4) + c] = v;
  }
}

// ---------- K4: copy branch scatter ----------
__global__ void copyprob_kernel(const float* __restrict__ attn, const int* __restrict__ src_ids,
                                const float* __restrict__ copyg, float* __restrict__ out) {
  unsigned r = blockIdx.x;
  unsigned tid = threadIdx.x;
  __shared__ float cp[CV_DIM];
  for (unsigned v = tid; v < CV_DIM; v += 128) cp[v] = 0.f;
  __syncthreads();
  unsigned batch = r >> 7;
  float g = copyg[r];
  for (unsigned s = tid; s < S_DIM; s += 128) {
    float a = attn[(size_t)r * S_DIM + s] * g;
    atomicAdd(&cp[src_ids[batch * S_DIM + s]], a);
  }
  __syncthreads();
  for (unsigned v = tid; v < CV_DIM; v += 128)
    out[(size_t)r * OUT_PITCH + N_VOCAB + v] = cp[v];
}

extern "C" void kernel_launch(void* const* d_in, const int* in_sizes, int n_in,
                              void* d_out, int out_size, void* d_ws, size_t ws_size,
                              hipStream_t stream) {
  const float* hidden    = (const float*)d_in[0];
  const float* copy_attn = (const float*)d_in[1];
  const float* src_map   = (const float*)d_in[2];
  const float* W         = (const float*)d_in[3];
  const float* bias      = (const float*)d_in[4];
  const float* w_copy    = (const float*)d_in[5];
  const float* b_copy    = (const float*)d_in[6];
  float* out = (float*)d_out;

  char* ws = (char*)d_ws;
  unsigned short* Wb = (unsigned short*)(ws + WB_OFF);
  unsigned short* Hb = (unsigned short*)(ws + HB_OFF);
  float* copyg   = (float*)(ws + COPYG_OFF);
  float* row_sum = (float*)(ws + RSUM_OFF);
  float* sscale  = (float*)(ws + SSCALE_OFF);
  int*   src_ids = (int*)(ws + SRCID_OFF);
  unsigned short* Eb = (unsigned short*)(ws + EB_OFF);

  const bool bf16_path = (ws_size >= WS_NEED_BF16);

  cvt_kernel<<<2048, 256, 0, stream>>>((const float4*)W, (ushort4*)Wb,
                                       (unsigned)(N_VOCAB * K_DIM / 4));
  cvt_kernel<<<1024, 256, 0, stream>>>((const float4*)hidden, (ushort4*)Hb,
                                       (unsigned)(M_ROWS * K_DIM / 4));
  copygate_kernel<<<M_ROWS / 4, 256, 0, stream>>>(hidden, w_copy, b_copy, copyg);
  srcids_kernel<<<(32 * S_DIM) / 4, 256, 0, stream>>>(src_map, src_ids);

  if (bf16_path) {
    gemm_exp_kernel<1><<<(M_ROWS / 128) * (N_VOCAB / 128), 256, 0, stream>>>(
        Hb, Wb, bias, out, Eb, row_sum);
    norm_scale_kernel<<<M_ROWS, 256, 0, stream>>>(Eb, copyg, out);
  } else {
    hipMemsetAsync(row_sum, 0, M_ROWS * sizeof(float), stream);
    gemm_exp_kernel<0><<<(M_ROWS / 128) * (N_VOCAB / 128), 256, 0, stream>>>(
        Hb, Wb, bias, out, Eb, row_sum);
    finalize_kernel<<<(M_ROWS + 255) / 256, 256, 0, stream>>>(row_sum, copyg, sscale);
    scale_kernel<<<4096, 256, 0, stream>>>((float4*)out, sscale);
  }

  copyprob_kernel<<<M_ROWS, 128, 0, stream>>>(copy_attn, src_ids, copyg, out);
}

// Round 7
// 411.902 us; speedup vs baseline: 1.0767x; 1.0767x over previous
//
#include <hip/hip_runtime.h>
#include <hip/hip_bf16.h>
#include <cstdint>
#include <cstddef>

// Problem dims
#define M_ROWS   4096     // B*T
#define N_VOCAB  32000    // V
#define K_DIM    512      // D
#define S_DIM    400
#define CV_DIM   600
#define OUT_PITCH 32600   // V + CV
#define PAD_IDX  1

typedef __attribute__((ext_vector_type(8))) short short8;
typedef __attribute__((ext_vector_type(8))) unsigned short ushort8;
typedef __attribute__((ext_vector_type(4))) float f32x4;

// ws layout
#define WB_OFF   0ull                       // W bf16: 32,768,000 B
#define HB_OFF   32768000ull                // hidden bf16: 4,194,304 B
#define COPYG_OFF 36962304ull
#define RSUM_OFF  36978688ull
#define SSCALE_OFF 36995072ull
#define SRCID_OFF 37011456ull               // 51,200 B
#define EB_OFF    37062656ull               // bf16 exp intermediate: 262,144,000 B
#define WS_NEED_BF16 (EB_OFF + 262144000ull)

__device__ inline void gload_lds16(const void* g, void* l) {
  __builtin_amdgcn_global_load_lds(
      (const __attribute__((address_space(1))) unsigned int*)g,
      (__attribute__((address_space(3))) unsigned int*)l, 16, 0, 0);
}

__device__ inline unsigned short f32_to_bf16_rn(float f) {
  unsigned u = __float_as_uint(f);
  u += 0x7FFFu + ((u >> 16) & 1u);
  return (unsigned short)(u >> 16);
}
__device__ inline float bf16_to_f32(unsigned short h) {
  return __uint_as_float((unsigned)h << 16);
}

// ---------- K1a: fp32 -> bf16 conversion (W only; hidden folded into copygate) ----------
__global__ void cvt_kernel(const float4* __restrict__ in, ushort4* __restrict__ out, unsigned n4) {
  unsigned stride = gridDim.x * blockDim.x;
  for (unsigned i = blockIdx.x * blockDim.x + threadIdx.x; i < n4; i += stride) {
    float4 v = in[i];
    ushort4 o;
    o.x = f32_to_bf16_rn(v.x);
    o.y = f32_to_bf16_rn(v.y);
    o.z = f32_to_bf16_rn(v.z);
    o.w = f32_to_bf16_rn(v.w);
    out[i] = o;
  }
}

// ---------- K1b: copy gate + hidden->bf16 (fused; one wave per row) ----------
__global__ void copygate_cvt_kernel(const float* __restrict__ hidden,
                                    const float* __restrict__ w_copy,
                                    const float* __restrict__ b_copy,
                                    float* __restrict__ copyg,
                                    unsigned short* __restrict__ Hb) {
  unsigned gw = (blockIdx.x * blockDim.x + threadIdx.x) >> 6;   // row
  unsigned lane = threadIdx.x & 63u;
  if (gw >= M_ROWS) return;
  const float4* h4 = (const float4*)(hidden + (size_t)gw * K_DIM);
  const float4* w4 = (const float4*)w_copy;
  float4 a0 = h4[lane * 2 + 0], w0 = w4[lane * 2 + 0];
  float4 a1 = h4[lane * 2 + 1], w1 = w4[lane * 2 + 1];
  float dot = a0.x * w0.x + a0.y * w0.y + a0.z * w0.z + a0.w * w0.w
            + a1.x * w1.x + a1.y * w1.y + a1.z * w1.z + a1.w * w1.w;
  // fused bf16 conversion of the row (each lane owns 8 contiguous elems)
  ushort8 hb;
  hb[0] = f32_to_bf16_rn(a0.x); hb[1] = f32_to_bf16_rn(a0.y);
  hb[2] = f32_to_bf16_rn(a0.z); hb[3] = f32_to_bf16_rn(a0.w);
  hb[4] = f32_to_bf16_rn(a1.x); hb[5] = f32_to_bf16_rn(a1.y);
  hb[6] = f32_to_bf16_rn(a1.z); hb[7] = f32_to_bf16_rn(a1.w);
  *(ushort8*)(Hb + (size_t)gw * K_DIM + lane * 8u) = hb;
  #pragma unroll
  for (int mask = 1; mask < 64; mask <<= 1) dot += __shfl_xor(dot, mask);
  if (lane == 0) copyg[gw] = 1.f / (1.f + __expf(-(dot + b_copy[0])));
}

// ---------- K1c: recover src_ids from one-hot src_map ----------
__global__ void srcids_kernel(const float* __restrict__ src_map, int* __restrict__ src_ids) {
  unsigned pos = (blockIdx.x * blockDim.x + threadIdx.x) >> 6;
  unsigned lane = threadIdx.x & 63u;
  if (pos >= 32 * S_DIM) return;
  const float* row = src_map + (size_t)pos * CV_DIM;
  int found = 1 << 30;
  for (int v = lane; v < CV_DIM; v += 64)
    if (row[v] > 0.5f) found = v;
  #pragma unroll
  for (int mask = 1; mask < 64; mask <<= 1) {
    int o = __shfl_xor(found, mask);
    found = found < o ? found : o;
  }
  if (lane == 0) src_ids[pos] = found;
}

// ---------- K2: 128x128 bf16 MFMA GEMM (R5 structure) + direct-store exp epilogue ----------
// 4 waves (2x2), BK=64, single 32 KB LDS, 2-barrier loop, T2 swizzle, 4 blocks/CU.
// MFMA operands SWAPPED: acc = mfma(bf, af) -> lane holds 4 CONSECUTIVE output
// columns (row = m*16+lc, cols = n*16+lr*4+j) => register-direct contiguous
// ushort4 stores; no LDS pack, no epilogue barriers.
template<int BF16OUT>
__global__ __launch_bounds__(256, 4)
void gemm_exp_kernel(const unsigned short* __restrict__ A,
                     const unsigned short* __restrict__ B,
                     const float* __restrict__ bias,
                     float* __restrict__ out,
                     unsigned short* __restrict__ Eb,
                     float* __restrict__ row_sum) {
  __shared__ unsigned short smem[16384];   // As | Bs, 16 KB each
  unsigned short* As = smem;
  unsigned short* Bs = smem + 8192;

  unsigned bid = blockIdx.x;
  // bijective XCD swizzle: 8000 blocks, 8000 % 8 == 0
  unsigned wg = (bid & 7u) * 1000u + (bid >> 3);
  unsigned mt = wg / 250u, nt = wg % 250u;
  unsigned m0 = mt * 128u, n0 = nt * 128u;
  unsigned tid = threadIdx.x;
  unsigned lane = tid & 63u;
  unsigned wid = tid >> 6;
  unsigned wm = wid >> 1, wn = wid & 1u;    // 2 x 2 wave grid, 64x64 per wave
  unsigned lr = lane >> 4, lc = lane & 15u;

  // swizzled read chunk offsets (ushort units) for ks=0/1
  const unsigned ch0 = (lr ^ (lc & 7u)) * 8u;
  const unsigned ch1 = ((lr + 4u) ^ (lc & 7u)) * 8u;

  // staging sources (kt-invariant): unit u = i*256 + tid, rr = u>>3, inverse-swz chunk
  const unsigned short* Asrc[4];
  const unsigned short* Bsrc[4];
  unsigned dst[4];
  #pragma unroll
  for (unsigned i = 0; i < 4; ++i) {
    unsigned u = i * 256u + tid;
    unsigned rr = u >> 3;                       // 0..127
    unsigned ch = (u & 7u) ^ (rr & 7u);         // inverse-swizzled source chunk
    dst[i] = u * 16u;                           // linear dest byte offset
    Asrc[i] = A + (size_t)(m0 + rr) * K_DIM + ch * 8u;
    Bsrc[i] = B + (size_t)(n0 + rr) * K_DIM + ch * 8u;
  }
  // fragment read row bases (ushort index)
  unsigned arow[4], brow[4];
  #pragma unroll
  for (int m = 0; m < 4; ++m) arow[m] = (wm * 64u + m * 16u + lc) * 64u;
  #pragma unroll
  for (int n = 0; n < 4; ++n) brow[n] = (wn * 64u + n * 16u + lc) * 64u;

  f32x4 acc[4][4] = {};

  for (unsigned kt = 0; kt < 8; ++kt) {
    unsigned k0 = kt * 64u;
    #pragma unroll
    for (unsigned i = 0; i < 4; ++i) {
      gload_lds16(Asrc[i] + k0, (char*)As + dst[i]);
      gload_lds16(Bsrc[i] + k0, (char*)Bs + dst[i]);
    }
    __syncthreads();   // compiler emits vmcnt(0) drain before barrier
    {
      short8 af[4][2], bf[4][2];
      #pragma unroll
      for (int m = 0; m < 4; ++m) {
        af[m][0] = *(const short8*)&As[arow[m] + ch0];
        af[m][1] = *(const short8*)&As[arow[m] + ch1];
      }
      #pragma unroll
      for (int n = 0; n < 4; ++n) {
        bf[n][0] = *(const short8*)&Bs[brow[n] + ch0];
        bf[n][1] = *(const short8*)&Bs[brow[n] + ch1];
      }
      // swapped operands: D "row" space = B rows (output cols), "col" = A rows
      #pragma unroll
      for (int ks = 0; ks < 2; ++ks)
        #pragma unroll
        for (int m = 0; m < 4; ++m)
          #pragma unroll
          for (int n = 0; n < 4; ++n)
            acc[m][n] = __builtin_amdgcn_mfma_f32_16x16x32_bf16(bf[n][ks], af[m][ks],
                                                                acc[m][n], 0, 0, 0);
    }
    __syncthreads();
  }

  // epilogue: acc[m][n][j] = logit(row = m0+wm*64+m*16+lc, col = n0+wn*64+n*16+lr*4+j)
  // bias hoist: per n, 4 consecutive cols -> one float4 (lr-dependent)
  float4 bv4[4];
  #pragma unroll
  for (int n = 0; n < 4; ++n)
    bv4[n] = *(const float4*)&bias[n0 + wn * 64u + n * 16u + lr * 4u];

  if (BF16OUT) {
    #pragma unroll
    for (int m = 0; m < 4; ++m) {
      unsigned grow = m0 + wm * 64u + m * 16u + lc;
      unsigned short* rowp = Eb + (size_t)grow * N_VOCAB;
      #pragma unroll
      for (int n = 0; n < 4; ++n) {
        unsigned gcol = n0 + wn * 64u + n * 16u + lr * 4u;
        float e0 = (gcol + 0u == PAD_IDX) ? 0.f : __expf(acc[m][n][0] + bv4[n].x);
        float e1 = (gcol + 1u == PAD_IDX) ? 0.f : __expf(acc[m][n][1] + bv4[n].y);
        float e2 = (gcol + 2u == PAD_IDX) ? 0.f : __expf(acc[m][n][2] + bv4[n].z);
        float e3 = (gcol + 3u == PAD_IDX) ? 0.f : __expf(acc[m][n][3] + bv4[n].w);
        ushort4 o;
        o.x = f32_to_bf16_rn(e0); o.y = f32_to_bf16_rn(e1);
        o.z = f32_to_bf16_rn(e2); o.w = f32_to_bf16_rn(e3);
        *(ushort4*)(rowp + gcol) = o;
      }
    }
  } else {
    // fallback: fp32 stores (float4-contiguous now) + atomic row sums
    #pragma unroll
    for (int m = 0; m < 4; ++m) {
      unsigned grow = m0 + wm * 64u + m * 16u + lc;
      float rs = 0.f;
      #pragma unroll
      for (int n = 0; n < 4; ++n) {
        unsigned gcol = n0 + wn * 64u + n * 16u + lr * 4u;
        float4 e;
        e.x = (gcol + 0u == PAD_IDX) ? 0.f : __expf(acc[m][n][0] + bv4[n].x);
        e.y = (gcol + 1u == PAD_IDX) ? 0.f : __expf(acc[m][n][1] + bv4[n].y);
        e.z = (gcol + 2u == PAD_IDX) ? 0.f : __expf(acc[m][n][2] + bv4[n].z);
        e.w = (gcol + 3u == PAD_IDX) ? 0.f : __expf(acc[m][n][3] + bv4[n].w);
        *(float4*)(out + (size_t)grow * OUT_PITCH + gcol) = e;
        rs += e.x + e.y + e.z + e.w;
      }
      // lane owns one row per lr-group; reduce across lr groups (lanes +16,+32)
      rs += __shfl_xor(rs, 16);
      rs += __shfl_xor(rs, 32);
      if (lr == 0) atomicAdd(&row_sum[grow], rs);
    }
  }
}

// ---------- K3: per-row sum + scale: out = Eb * (1-gate)/sum ----------
__global__ __launch_bounds__(256)
void norm_scale_kernel(const unsigned short* __restrict__ Eb,
                       const float* __restrict__ copyg,
                       float* __restrict__ out) {
  unsigned r = blockIdx.x;
  unsigned tid = threadIdx.x;
  const ushort8* src = (const ushort8*)(Eb + (size_t)r * N_VOCAB);   // 4000 chunks
  ushort8 v[16];
  float lsum = 0.f;
  #pragma unroll
  for (int i = 0; i < 16; ++i) {
    unsigned c = (unsigned)i * 256u + tid;
    if (c < 4000u) {
      v[i] = src[c];
      #pragma unroll
      for (int k = 0; k < 8; ++k) lsum += bf16_to_f32(v[i][k]);
    }
  }
  #pragma unroll
  for (int mask = 1; mask < 64; mask <<= 1) lsum += __shfl_xor(lsum, mask);
  __shared__ float wsum[4];
  if ((tid & 63u) == 0) wsum[tid >> 6] = lsum;
  __syncthreads();
  float s = (1.f - copyg[r]) / (wsum[0] + wsum[1] + wsum[2] + wsum[3]);
  float* dst = out + (size_t)r * OUT_PITCH;
  #pragma unroll
  for (int i = 0; i < 16; ++i) {
    unsigned c = (unsigned)i * 256u + tid;
    if (c < 4000u) {
      float4 lo, hi;
      lo.x = bf16_to_f32(v[i][0]) * s; lo.y = bf16_to_f32(v[i][1]) * s;
      lo.z = bf16_to_f32(v[i][2]) * s; lo.w = bf16_to_f32(v[i][3]) * s;
      hi.x = bf16_to_f32(v[i][4]) * s; hi.y = bf16_to_f32(v[i][5]) * s;
      hi.z = bf16_to_f32(v[i][6]) * s; hi.w = bf16_to_f32(v[i][7]) * s;
      float4* o = (float4*)(dst + c * 8u);
      o[0] = lo; o[1] = hi;
    }
  }
}

// ---------- fallback-path kernels ----------
__global__ void finalize_kernel(const float* __restrict__ row_sum, const float* __restrict__ copyg,
                                float* __restrict__ sscale) {
  unsigned r = blockIdx.x * blockDim.x + threadIdx.x;
  if (r < M_ROWS) sscale[r] = (1.f - copyg[r]) / row_sum[r];
}

__global__ void scale_kernel(float4* __restrict__ out, const float* __restrict__ sscale) {
  const unsigned total = M_ROWS * (N_VOCAB / 4);
  unsigned stride = gridDim.x * blockDim.x;
  for (unsigned i = blockIdx.x * blockDim.x + threadIdx.x; i < total; i += stride) {
    unsigned r = i / (N_VOCAB / 4);
    unsigned c = i % (N_VOCAB / 4);
    float s = sscale[r];
    float4 v = out[(size_t)r * (OUT_PITCH / 4) + c];
    v.x *= s; v.y *= s; v.z *= s; v.w *= s;
    out[(size_t)r * (OUT_PITCH / 4) + c] = v;
  }
}

// ---------- K4: copy branch scatter ----------
__global__ void copyprob_kernel(const float* __restrict__ attn, const int* __restrict__ src_ids,
                                const float* __restrict__ copyg, float* __restrict__ out) {
  unsigned r = blockIdx.x;
  unsigned tid = threadIdx.x;
  __shared__ float cp[CV_DIM];
  for (unsigned v = tid; v < CV_DIM; v += 128) cp[v] = 0.f;
  __syncthreads();
  unsigned batch = r >> 7;
  float g = copyg[r];
  for (unsigned s = tid; s < S_DIM; s += 128) {
    float a = attn[(size_t)r * S_DIM + s] * g;
    atomicAdd(&cp[src_ids[batch * S_DIM + s]], a);
  }
  __syncthreads();
  for (unsigned v = tid; v < CV_DIM; v += 128)
    out[(size_t)r * OUT_PITCH + N_VOCAB + v] = cp[v];
}

extern "C" void kernel_launch(void* const* d_in, const int* in_sizes, int n_in,
                              void* d_out, int out_size, void* d_ws, size_t ws_size,
                              hipStream_t stream) {
  const float* hidden    = (const float*)d_in[0];
  const float* copy_attn = (const float*)d_in[1];
  const float* src_map   = (const float*)d_in[2];
  const float* W         = (const float*)d_in[3];
  const float* bias      = (const float*)d_in[4];
  const float* w_copy    = (const float*)d_in[5];
  const float* b_copy    = (const float*)d_in[6];
  float* out = (float*)d_out;

  char* ws = (char*)d_ws;
  unsigned short* Wb = (unsigned short*)(ws + WB_OFF);
  unsigned short* Hb = (unsigned short*)(ws + HB_OFF);
  float* copyg   = (float*)(ws + COPYG_OFF);
  float* row_sum = (float*)(ws + RSUM_OFF);
  float* sscale  = (float*)(ws + SSCALE_OFF);
  int*   src_ids = (int*)(ws + SRCID_OFF);
  unsigned short* Eb = (unsigned short*)(ws + EB_OFF);

  const bool bf16_path = (ws_size >= WS_NEED_BF16);

  cvt_kernel<<<2048, 256, 0, stream>>>((const float4*)W, (ushort4*)Wb,
                                       (unsigned)(N_VOCAB * K_DIM / 4));
  copygate_cvt_kernel<<<M_ROWS / 4, 256, 0, stream>>>(hidden, w_copy, b_copy, copyg, Hb);
  srcids_kernel<<<(32 * S_DIM) / 4, 256, 0, stream>>>(src_map, src_ids);

  if (bf16_path) {
    gemm_exp_kernel<1><<<(M_ROWS / 128) * (N_VOCAB / 128), 256, 0, stream>>>(
        Hb, Wb, bias, out, Eb, row_sum);
    norm_scale_kernel<<<M_ROWS, 256, 0, stream>>>(Eb, copyg, out);
  } else {
    hipMemsetAsync(row_sum, 0, M_ROWS * sizeof(float), stream);
    gemm_exp_kernel<0><<<(M_ROWS / 128) * (N_VOCAB / 128), 256, 0, stream>>>(
        Hb, Wb, bias, out, Eb, row_sum);
    finalize_kernel<<<(M_ROWS + 255) / 256, 256, 0, stream>>>(row_sum, copyg, sscale);
    scale_kernel<<<4096, 256, 0, stream>>>((float4*)out, sscale);
  }

  copyprob_kernel<<<M_ROWS, 128, 0, stream>>>(copy_attn, src_ids, copyg, out);
}

// Round 8
// 410.534 us; speedup vs baseline: 1.0803x; 1.0033x over previous
//
#include <hip/hip_runtime.h>
#include <hip/hip_bf16.h>
#include <cstdint>
#include <cstddef>

// Problem dims
#define M_ROWS   4096     // B*T
#define N_VOCAB  32000    // V
#define K_DIM    512      // D
#define S_DIM    400
#define CV_DIM   600
#define OUT_PITCH 32600   // V + CV
#define PAD_IDX  1

typedef __attribute__((ext_vector_type(8))) short short8;
typedef __attribute__((ext_vector_type(8))) unsigned short ushort8;
typedef __attribute__((ext_vector_type(4))) float f32x4;

// ws layout
#define WB_OFF   0ull                       // W bf16: 32,768,000 B
#define HB_OFF   32768000ull                // hidden bf16: 4,194,304 B
#define COPYG_OFF 36962304ull
#define RSUM_OFF  36978688ull
#define SSCALE_OFF 36995072ull
#define SRCID_OFF 37011456ull               // 51,200 B
#define EB_OFF    37062656ull               // bf16 exp intermediate: 262,144,000 B
#define WS_NEED_BF16 (EB_OFF + 262144000ull)

__device__ inline void gload_lds16(const void* g, void* l) {
  __builtin_amdgcn_global_load_lds(
      (const __attribute__((address_space(1))) unsigned int*)g,
      (__attribute__((address_space(3))) unsigned int*)l, 16, 0, 0);
}

__device__ inline unsigned short f32_to_bf16_rn(float f) {
  unsigned u = __float_as_uint(f);
  u += 0x7FFFu + ((u >> 16) & 1u);
  return (unsigned short)(u >> 16);
}
__device__ inline float bf16_to_f32(unsigned short h) {
  return __uint_as_float((unsigned)h << 16);
}

// ---------- K1a: fp32 -> bf16 conversion (W only) ----------
__global__ void cvt_kernel(const float4* __restrict__ in, ushort4* __restrict__ out, unsigned n4) {
  unsigned stride = gridDim.x * blockDim.x;
  for (unsigned i = blockIdx.x * blockDim.x + threadIdx.x; i < n4; i += stride) {
    float4 v = in[i];
    ushort4 o;
    o.x = f32_to_bf16_rn(v.x);
    o.y = f32_to_bf16_rn(v.y);
    o.z = f32_to_bf16_rn(v.z);
    o.w = f32_to_bf16_rn(v.w);
    out[i] = o;
  }
}

// ---------- K1b: copy gate + hidden->bf16 (fused; one wave per row) ----------
__global__ void copygate_cvt_kernel(const float* __restrict__ hidden,
                                    const float* __restrict__ w_copy,
                                    const float* __restrict__ b_copy,
                                    float* __restrict__ copyg,
                                    unsigned short* __restrict__ Hb) {
  unsigned gw = (blockIdx.x * blockDim.x + threadIdx.x) >> 6;   // row
  unsigned lane = threadIdx.x & 63u;
  if (gw >= M_ROWS) return;
  const float4* h4 = (const float4*)(hidden + (size_t)gw * K_DIM);
  const float4* w4 = (const float4*)w_copy;
  float4 a0 = h4[lane * 2 + 0], w0 = w4[lane * 2 + 0];
  float4 a1 = h4[lane * 2 + 1], w1 = w4[lane * 2 + 1];
  float dot = a0.x * w0.x + a0.y * w0.y + a0.z * w0.z + a0.w * w0.w
            + a1.x * w1.x + a1.y * w1.y + a1.z * w1.z + a1.w * w1.w;
  ushort8 hb;
  hb[0] = f32_to_bf16_rn(a0.x); hb[1] = f32_to_bf16_rn(a0.y);
  hb[2] = f32_to_bf16_rn(a0.z); hb[3] = f32_to_bf16_rn(a0.w);
  hb[4] = f32_to_bf16_rn(a1.x); hb[5] = f32_to_bf16_rn(a1.y);
  hb[6] = f32_to_bf16_rn(a1.z); hb[7] = f32_to_bf16_rn(a1.w);
  *(ushort8*)(Hb + (size_t)gw * K_DIM + lane * 8u) = hb;
  #pragma unroll
  for (int mask = 1; mask < 64; mask <<= 1) dot += __shfl_xor(dot, mask);
  if (lane == 0) copyg[gw] = 1.f / (1.f + __expf(-(dot + b_copy[0])));
}

// ---------- K1c: recover src_ids from one-hot src_map ----------
__global__ void srcids_kernel(const float* __restrict__ src_map, int* __restrict__ src_ids) {
  unsigned pos = (blockIdx.x * blockDim.x + threadIdx.x) >> 6;
  unsigned lane = threadIdx.x & 63u;
  if (pos >= 32 * S_DIM) return;
  const float* row = src_map + (size_t)pos * CV_DIM;
  int found = 1 << 30;
  for (int v = lane; v < CV_DIM; v += 64)
    if (row[v] > 0.5f) found = v;
  #pragma unroll
  for (int mask = 1; mask < 64; mask <<= 1) {
    int o = __shfl_xor(found, mask);
    found = found < o ? found : o;
  }
  if (lane == 0) src_ids[pos] = found;
}

// ---------- K2: 256x128 bf16 MFMA GEMM + direct-store exp epilogue ----------
// 8 waves (4M x 2N), each wave 64x64 (4x4 frags of 16x16x32), BK=64,
// single 48 KB LDS, 2-barrier loop, T2 swizzle, 2 blocks/CU (16 waves/CU).
// Reuse-aware block map: per XCD an L2-resident 1MB A-slab (mt-fast x4),
// B-half streamed once. MFMA operands swapped (R7): lane holds 4 consecutive
// output cols -> register-direct ushort4 stores.
template<int BF16OUT>
__global__ __launch_bounds__(512, 2)
void gemm_exp_kernel(const unsigned short* __restrict__ A,
                     const unsigned short* __restrict__ B,
                     const float* __restrict__ bias,
                     float* __restrict__ out,
                     unsigned short* __restrict__ Eb,
                     float* __restrict__ row_sum) {
  __shared__ unsigned short smem[24576];   // As 32 KB | Bs 16 KB
  unsigned short* As = smem;               // [256][64] swizzled
  unsigned short* Bs = smem + 16384;       // [128][64] swizzled

  unsigned bid = blockIdx.x;
  // reuse-aware bijective map over 4000 blocks (16 mt x 250 nt):
  // xcd = bid&7 -> slab (4 mt) + nt-half; local mt-fast x4 for A L2-residency.
  unsigned xcd = bid & 7u, local = bid >> 3;      // local 0..499
  unsigned slab = xcd >> 1, half = xcd & 1u;
  unsigned nt = half * 125u + (local >> 2);
  unsigned mt = slab * 4u + (local & 3u);
  unsigned m0 = mt * 256u, n0 = nt * 128u;

  unsigned tid = threadIdx.x;
  unsigned lane = tid & 63u;
  unsigned wid = tid >> 6;
  unsigned wm = wid >> 1, wn = wid & 1u;    // 4 x 2 wave grid, 64x64 per wave
  unsigned lr = lane >> 4, lc = lane & 15u;

  // swizzled read chunk offsets (ushort units) for ks=0/1
  const unsigned ch0 = (lr ^ (lc & 7u)) * 8u;
  const unsigned ch1 = ((lr + 4u) ^ (lc & 7u)) * 8u;

  // staging: A 2048 units (i<4), B 1024 units (i<2); unit u -> row u>>3, chunk u&7
  const unsigned short* Asrc[4];
  const unsigned short* Bsrc[2];
  unsigned dstA[4], dstB[2];
  #pragma unroll
  for (unsigned i = 0; i < 4; ++i) {
    unsigned u = i * 512u + tid;
    unsigned rr = u >> 3;                       // 0..255
    unsigned ch = (u & 7u) ^ (rr & 7u);         // inverse-swizzled source chunk
    dstA[i] = u * 16u;
    Asrc[i] = A + (size_t)(m0 + rr) * K_DIM + ch * 8u;
  }
  #pragma unroll
  for (unsigned i = 0; i < 2; ++i) {
    unsigned u = i * 512u + tid;
    unsigned rr = u >> 3;                       // 0..127
    unsigned ch = (u & 7u) ^ (rr & 7u);
    dstB[i] = u * 16u;
    Bsrc[i] = B + (size_t)(n0 + rr) * K_DIM + ch * 8u;
  }
  // fragment read row bases (ushort index)
  unsigned arow[4], brow[4];
  #pragma unroll
  for (int m = 0; m < 4; ++m) arow[m] = (wm * 64u + m * 16u + lc) * 64u;
  #pragma unroll
  for (int n = 0; n < 4; ++n) brow[n] = 16384u + (wn * 64u + n * 16u + lc) * 64u;

  f32x4 acc[4][4] = {};

  for (unsigned kt = 0; kt < 8; ++kt) {
    unsigned k0 = kt * 64u;
    #pragma unroll
    for (unsigned i = 0; i < 4; ++i)
      gload_lds16(Asrc[i] + k0, (char*)As + dstA[i]);
    #pragma unroll
    for (unsigned i = 0; i < 2; ++i)
      gload_lds16(Bsrc[i] + k0, (char*)smem + 32768u + dstB[i]);
    __syncthreads();   // compiler emits vmcnt(0) drain before barrier
    {
      short8 af[4][2], bf[4][2];
      #pragma unroll
      for (int m = 0; m < 4; ++m) {
        af[m][0] = *(const short8*)&As[arow[m] + ch0];
        af[m][1] = *(const short8*)&As[arow[m] + ch1];
      }
      #pragma unroll
      for (int n = 0; n < 4; ++n) {
        bf[n][0] = *(const short8*)&smem[brow[n] + ch0];
        bf[n][1] = *(const short8*)&smem[brow[n] + ch1];
      }
      // swapped operands: lane holds 4 consecutive output columns
      #pragma unroll
      for (int ks = 0; ks < 2; ++ks)
        #pragma unroll
        for (int m = 0; m < 4; ++m)
          #pragma unroll
          for (int n = 0; n < 4; ++n)
            acc[m][n] = __builtin_amdgcn_mfma_f32_16x16x32_bf16(bf[n][ks], af[m][ks],
                                                                acc[m][n], 0, 0, 0);
    }
    __syncthreads();
  }

  // epilogue: acc[m][n][j] = logit(row = m0+wm*64+m*16+lc, col = n0+wn*64+n*16+lr*4+j)
  float4 bv4[4];
  #pragma unroll
  for (int n = 0; n < 4; ++n)
    bv4[n] = *(const float4*)&bias[n0 + wn * 64u + n * 16u + lr * 4u];

  if (BF16OUT) {
    #pragma unroll
    for (int m = 0; m < 4; ++m) {
      unsigned grow = m0 + wm * 64u + m * 16u + lc;
      unsigned short* rowp = Eb + (size_t)grow * N_VOCAB;
      #pragma unroll
      for (int n = 0; n < 4; ++n) {
        unsigned gcol = n0 + wn * 64u + n * 16u + lr * 4u;
        float e0 = (gcol + 0u == PAD_IDX) ? 0.f : __expf(acc[m][n][0] + bv4[n].x);
        float e1 = (gcol + 1u == PAD_IDX) ? 0.f : __expf(acc[m][n][1] + bv4[n].y);
        float e2 = (gcol + 2u == PAD_IDX) ? 0.f : __expf(acc[m][n][2] + bv4[n].z);
        float e3 = (gcol + 3u == PAD_IDX) ? 0.f : __expf(acc[m][n][3] + bv4[n].w);
        ushort4 o;
        o.x = f32_to_bf16_rn(e0); o.y = f32_to_bf16_rn(e1);
        o.z = f32_to_bf16_rn(e2); o.w = f32_to_bf16_rn(e3);
        *(ushort4*)(rowp + gcol) = o;
      }
    }
  } else {
    // fallback: fp32 float4 stores + atomic row sums
    #pragma unroll
    for (int m = 0; m < 4; ++m) {
      unsigned grow = m0 + wm * 64u + m * 16u + lc;
      float rs = 0.f;
      #pragma unroll
      for (int n = 0; n < 4; ++n) {
        unsigned gcol = n0 + wn * 64u + n * 16u + lr * 4u;
        float4 e;
        e.x = (gcol + 0u == PAD_IDX) ? 0.f : __expf(acc[m][n][0] + bv4[n].x);
        e.y = (gcol + 1u == PAD_IDX) ? 0.f : __expf(acc[m][n][1] + bv4[n].y);
        e.z = (gcol + 2u == PAD_IDX) ? 0.f : __expf(acc[m][n][2] + bv4[n].z);
        e.w = (gcol + 3u == PAD_IDX) ? 0.f : __expf(acc[m][n][3] + bv4[n].w);
        *(float4*)(out + (size_t)grow * OUT_PITCH + gcol) = e;
        rs += e.x + e.y + e.z + e.w;
      }
      rs += __shfl_xor(rs, 16);
      rs += __shfl_xor(rs, 32);
      if (lr == 0) atomicAdd(&row_sum[grow], rs);
    }
  }
}

// ---------- K3: per-row sum + scale: out = Eb * (1-gate)/sum ----------
__global__ __launch_bounds__(256)
void norm_scale_kernel(const unsigned short* __restrict__ Eb,
                       const float* __restrict__ copyg,
                       float* __restrict__ out) {
  unsigned r = blockIdx.x;
  unsigned tid = threadIdx.x;
  const ushort8* src = (const ushort8*)(Eb + (size_t)r * N_VOCAB);   // 4000 chunks
  ushort8 v[16];
  float lsum = 0.f;
  #pragma unroll
  for (int i = 0; i < 16; ++i) {
    unsigned c = (unsigned)i * 256u + tid;
    if (c < 4000u) {
      v[i] = src[c];
      #pragma unroll
      for (int k = 0; k < 8; ++k) lsum += bf16_to_f32(v[i][k]);
    }
  }
  #pragma unroll
  for (int mask = 1; mask < 64; mask <<= 1) lsum += __shfl_xor(lsum, mask);
  __shared__ float wsum[4];
  if ((tid & 63u) == 0) wsum[tid >> 6] = lsum;
  __syncthreads();
  float s = (1.f - copyg[r]) / (wsum[0] + wsum[1] + wsum[2] + wsum[3]);
  float* dst = out + (size_t)r * OUT_PITCH;
  #pragma unroll
  for (int i = 0; i < 16; ++i) {
    unsigned c = (unsigned)i * 256u + tid;
    if (c < 4000u) {
      float4 lo, hi;
      lo.x = bf16_to_f32(v[i][0]) * s; lo.y = bf16_to_f32(v[i][1]) * s;
      lo.z = bf16_to_f32(v[i][2]) * s; lo.w = bf16_to_f32(v[i][3]) * s;
      hi.x = bf16_to_f32(v[i][4]) * s; hi.y = bf16_to_f32(v[i][5]) * s;
      hi.z = bf16_to_f32(v[i][6]) * s; hi.w = bf16_to_f32(v[i][7]) * s;
      float4* o = (float4*)(dst + c * 8u);
      o[0] = lo; o[1] = hi;
    }
  }
}

// ---------- fallback-path kernels ----------
__global__ void finalize_kernel(const float* __restrict__ row_sum, const float* __restrict__ copyg,
                                float* __restrict__ sscale) {
  unsigned r = blockIdx.x * blockDim.x + threadIdx.x;
  if (r < M_ROWS) sscale[r] = (1.f - copyg[r]) / row_sum[r];
}

__global__ void scale_kernel(float4* __restrict__ out, const float* __restrict__ sscale) {
  const unsigned total = M_ROWS * (N_VOCAB / 4);
  unsigned stride = gridDim.x * blockDim.x;
  for (unsigned i = blockIdx.x * blockDim.x + threadIdx.x; i < total; i += stride) {
    unsigned r = i / (N_VOCAB / 4);
    unsigned c = i % (N_VOCAB / 4);
    float s = sscale[r];
    float4 v = out[(size_t)r * (OUT_PITCH / 4) + c];
    v.x *= s; v.y *= s; v.z *= s; v.w *= s;
    out[(size_t)r * (OUT_PITCH / 4) + c] = v;
  }
}

// ---------- K4: copy branch scatter ----------
__global__ void copyprob_kernel(const float* __restrict__ attn, const int* __restrict__ src_ids,
                                const float* __restrict__ copyg, float* __restrict__ out) {
  unsigned r = blockIdx.x;
  unsigned tid = threadIdx.x;
  __shared__ float cp[CV_DIM];
  for (unsigned v = tid; v < CV_DIM; v += 128) cp[v] = 0.f;
  __syncthreads();
  unsigned batch = r >> 7;
  float g = copyg[r];
  for (unsigned s = tid; s < S_DIM; s += 128) {
    float a = attn[(size_t)r * S_DIM + s] * g;
    atomicAdd(&cp[src_ids[batch * S_DIM + s]], a);
  }
  __syncthreads();
  for (unsigned v = tid; v < CV_DIM; v += 128)
    out[(size_t)r * OUT_PITCH + N_VOCAB + v] = cp[v];
}

extern "C" void kernel_launch(void* const* d_in, const int* in_sizes, int n_in,
                              void* d_out, int out_size, void* d_ws, size_t ws_size,
                              hipStream_t stream) {
  const float* hidden    = (const float*)d_in[0];
  const float* copy_attn = (const float*)d_in[1];
  const float* src_map   = (const float*)d_in[2];
  const float* W         = (const float*)d_in[3];
  const float* bias      = (const float*)d_in[4];
  const float* w_copy    = (const float*)d_in[5];
  const float* b_copy    = (const float*)d_in[6];
  float* out = (float*)d_out;

  char* ws = (char*)d_ws;
  unsigned short* Wb = (unsigned short*)(ws + WB_OFF);
  unsigned short* Hb = (unsigned short*)(ws + HB_OFF);
  float* copyg   = (float*)(ws + COPYG_OFF);
  float* row_sum = (float*)(ws + RSUM_OFF);
  float* sscale  = (float*)(ws + SSCALE_OFF);
  int*   src_ids = (int*)(ws + SRCID_OFF);
  unsigned short* Eb = (unsigned short*)(ws + EB_OFF);

  const bool bf16_path = (ws_size >= WS_NEED_BF16);

  cvt_kernel<<<2048, 256, 0, stream>>>((const float4*)W, (ushort4*)Wb,
                                       (unsigned)(N_VOCAB * K_DIM / 4));
  copygate_cvt_kernel<<<M_ROWS / 4, 256, 0, stream>>>(hidden, w_copy, b_copy, copyg, Hb);
  srcids_kernel<<<(32 * S_DIM) / 4, 256, 0, stream>>>(src_map, src_ids);

  // main GEMM: 16 x 250 tiles of 256x128, 512 threads, 2 blocks/CU
  if (bf16_path) {
    gemm_exp_kernel<1><<<(M_ROWS / 256) * (N_VOCAB / 128), 512, 0, stream>>>(
        Hb, Wb, bias, out, Eb, row_sum);
    norm_scale_kernel<<<M_ROWS, 256, 0, stream>>>(Eb, copyg, out);
  } else {
    hipMemsetAsync(row_sum, 0, M_ROWS * sizeof(float), stream);
    gemm_exp_kernel<0><<<(M_ROWS / 256) * (N_VOCAB / 128), 512, 0, stream>>>(
        Hb, Wb, bias, out, Eb, row_sum);
    finalize_kernel<<<(M_ROWS + 255) / 256, 256, 0, stream>>>(row_sum, copyg, sscale);
    scale_kernel<<<4096, 256, 0, stream>>>((float4*)out, sscale);
  }

  copyprob_kernel<<<M_ROWS, 128, 0, stream>>>(copy_attn, src_ids, copyg, out);
}